// Round 5
// baseline (61.773 us; speedup 1.0000x reference)
//
#include <hip/hip_runtime.h>

typedef __attribute__((ext_vector_type(8))) short short8;
typedef __attribute__((ext_vector_type(16))) float f32x16;
typedef unsigned short ushort16_t;

#define MFMA(A, B, C) __builtin_amdgcn_mfma_f32_32x32x16_bf16(A, B, C, 0, 0, 0)

__device__ __forceinline__ float4 ldf4(const float* p) { return *(const float4*)p; }
__device__ __forceinline__ short8 ld8(const void* p) { return *(const short8*)p; }

__device__ __forceinline__ short8 mk8(unsigned w0, unsigned w1, unsigned w2, unsigned w3) {
    union { unsigned u[4]; short8 s; } t;
    t.u[0] = w0; t.u[1] = w1; t.u[2] = w2; t.u[3] = w3;
    return t.s;
}
// pack bf16-truncations of (a,b): low16 = top16(a), high16 = top16(b)
__device__ __forceinline__ unsigned packhi2(float a, float b) {
    return __builtin_amdgcn_perm(__float_as_uint(b), __float_as_uint(a), 0x07060302u);
}
__device__ __forceinline__ float lopart(float v) {
    return v - __uint_as_float(__float_as_uint(v) & 0xFFFF0000u);
}
// v_permlane32_swap: lo' = [lo_lo, hi_lo], hi' = [lo_hi, hi_hi]
__device__ __forceinline__ void plswap(unsigned& lo, unsigned& hi) {
    asm("v_permlane32_swap_b32 %0, %1" : "+v"(lo), "+v"(hi));
}

__device__ __forceinline__ ushort16_t h16(float x) { return (ushort16_t)(__float_as_uint(x) >> 16); }
__device__ __forceinline__ float fh(ushort16_t u) { return __uint_as_float(((unsigned)u) << 16); }

// ---------------- prepack: weights -> bf16 fragment tables in d_ws ----------------
// w1t : [49 steps][32 rows o][2 half][8 j] bf16 (hi only), rows>=20 zero. 50176 B.
// midt: [29 layers][32 rows o][2 half][ A0h(8) A1h(8) A0l(8) A1l(8) ] bf16. 118784 B.
//   A1h j0..3 = W[o][16..19] (half0), j4 = bias_hi, j5 = bias_lo, j6,7 = 0
//   A1l j0..3 = lopart(W[o][16..19]) (half0), j4..7 = 0
//   layer 28 = fc30 (rows>=10 zero).
__global__ void prepack(const float* __restrict__ W1,
                        const float* __restrict__ Wmid, const float* __restrict__ bmid,
                        const float* __restrict__ W30, const float* __restrict__ b30,
                        ushort16_t* __restrict__ w1t, ushort16_t* __restrict__ midt)
{
    const int tid = blockIdx.x * 256 + threadIdx.x;
    const int nth = gridDim.x * 256;
    // W1 table: i = s*512 + o*16 + hf*8 + j
    for (int i = tid; i < 49 * 512; i += nth) {
        const int j = i & 7, hf = (i >> 3) & 1, o = (i >> 4) & 31, s = i >> 9;
        const float v = (o < 20) ? W1[o * 784 + s * 16 + hf * 8 + j] : 0.f;
        w1t[i] = h16(v);
    }
    // mid entries: e = l*64 + o*2 + hf
    for (int e = tid; e < 29 * 64; e += nth) {
        const int hf = e & 1, o = (e >> 1) & 31, l = e >> 6;
        ushort16_t v[32];
#pragma unroll
        for (int i = 0; i < 32; ++i) v[i] = 0;
        const bool lastl = (l == 28);
        const int omax = lastl ? 10 : 20;
        if (o < omax) {
            const float* wr = lastl ? (W30 + o * 20) : (Wmid + l * 400 + o * 20);
            const float bias = lastl ? b30[o] : bmid[l * 20 + o];
#pragma unroll
            for (int j = 0; j < 8; ++j) {
                const float w = wr[hf * 8 + j];
                v[j]      = h16(w);
                v[16 + j] = h16(w - fh(h16(w)));
            }
            if (hf == 0) {
#pragma unroll
                for (int j = 0; j < 4; ++j) {
                    const float w = wr[16 + j];
                    v[8 + j]  = h16(w);
                    v[24 + j] = h16(w - fh(h16(w)));
                }
                v[12] = h16(bias);                   // A1h j4 = bias_hi  (x B1h k20=1.0)
                v[13] = h16(bias - fh(h16(bias)));   // A1h j5 = bias_lo  (x B1l k21=1.0)
            }
        }
#pragma unroll
        for (int i = 0; i < 32; ++i) midt[e * 32 + i] = v[i];
    }
}

// ---------------- main: fc1 (2-way K-split, bf16) + mids (hi/lo) ----------------
// Block = 4 waves = 2 tiles of 32 rows. wv&1 = k-half of fc1 (cols 0..399 / 400..783).
// A=W rows o=lane&31, B cols r=lane&31, k-slot = 8*(lane>>5)+j (shared map -> HW perm cancels).
// C/D: col=lane&31, row=(reg&3)+8*(reg>>2)+4*(lane>>5).
__global__ __launch_bounds__(256, 4)
void mlp_main(const float* __restrict__ x, const float* __restrict__ b1p,
              const ushort16_t* __restrict__ w1t, const ushort16_t* __restrict__ midt,
              float* __restrict__ out, int nrows)
{
    __shared__ float red[2][16][64];

    const int lane = threadIdx.x & 63;
    const int wv   = threadIdx.x >> 6;
    const int kw   = wv & 1;            // fc1 k-half
    const int tl   = wv >> 1;           // tile within block
    const int tile = blockIdx.x * 2 + tl;
    const int r0   = tile * 32;
    if (r0 >= nrows) return;
    const int colr = lane & 31;
    const int half = lane >> 5;
    const int row  = r0 + colr;

    // ---- fc1: steps of 16 cols. kw0: s=0..24 (tail 24), kw1: s=25..48 ----
    const int sbeg = kw ? 25 : 0;
    const float* xp = x + (size_t)row * 784 + half * 8 + sbeg * 16;
    const ushort16_t* at = w1t + sbeg * 512 + colr * 16 + half * 8;

    f32x16 acc;
#pragma unroll
    for (int r = 0; r < 16; ++r) acc[r] = 0.f;

    // preload chunk 0 (2 steps)
    float4 a0 = ldf4(xp),      a1 = ldf4(xp + 4);
    float4 a2 = ldf4(xp + 16), a3 = ldf4(xp + 20);
    short8 Aa0 = ld8(at), Aa1 = ld8(at + 512);

#pragma unroll 1
    for (int cc = 0; cc < 6; ++cc) {
        // issue loads for chunk 2cc+1
        const float* q = xp + (2 * cc + 1) * 32;
        const float4 c0 = ldf4(q),      c1 = ldf4(q + 4);
        const float4 c2 = ldf4(q + 16), c3 = ldf4(q + 20);
        const short8 Ab0 = ld8(at + (2 * cc + 1) * 1024);
        const short8 Ab1 = ld8(at + (2 * cc + 1) * 1024 + 512);
        // compute chunk 2cc
        acc = MFMA(Aa0, mk8(packhi2(a0.x, a0.y), packhi2(a0.z, a0.w),
                            packhi2(a1.x, a1.y), packhi2(a1.z, a1.w)), acc);
        acc = MFMA(Aa1, mk8(packhi2(a2.x, a2.y), packhi2(a2.z, a2.w),
                            packhi2(a3.x, a3.y), packhi2(a3.z, a3.w)), acc);
        // issue loads for chunk 2cc+2
        if (cc < 5) {
            const float* q2 = xp + (2 * cc + 2) * 32;
            a0 = ldf4(q2);      a1 = ldf4(q2 + 4);
            a2 = ldf4(q2 + 16); a3 = ldf4(q2 + 20);
            Aa0 = ld8(at + (2 * cc + 2) * 1024);
            Aa1 = ld8(at + (2 * cc + 2) * 1024 + 512);
        }
        // compute chunk 2cc+1
        acc = MFMA(Ab0, mk8(packhi2(c0.x, c0.y), packhi2(c0.z, c0.w),
                            packhi2(c1.x, c1.y), packhi2(c1.z, c1.w)), acc);
        acc = MFMA(Ab1, mk8(packhi2(c2.x, c2.y), packhi2(c2.z, c2.w),
                            packhi2(c3.x, c3.y), packhi2(c3.z, c3.w)), acc);
    }
    if (!kw) { // tail step s=24
        const float4 t0 = ldf4(xp + 384), t1 = ldf4(xp + 388);
        const short8 At = ld8(at + 24 * 512);
        acc = MFMA(At, mk8(packhi2(t0.x, t0.y), packhi2(t0.z, t0.w),
                           packhi2(t1.x, t1.y), packhi2(t1.z, t1.w)), acc);
    }

    // ---- K-split reduce ----
    if (kw) {
#pragma unroll
        for (int r = 0; r < 16; ++r) red[tl][r][lane] = acc[r];
    }
    __syncthreads();
    if (kw) return;
#pragma unroll
    for (int r = 0; r < 16; ++r) acc[r] += red[tl][r][lane];

    // bias + relu (pad regs garbage-but-finite, never consumed)
    float Hv[16];
#pragma unroll
    for (int r = 0; r < 16; ++r) {
        const int o = (r & 3) + 8 * (r >> 2) + 4 * half;
        Hv[r] = fmaxf(acc[r] + b1p[o < 20 ? o : 0], 0.f);
    }

    // ---- fc2..fc30: prepacked A hi/lo + bias-in-k, H hi/lo ----
    const char* ap = (const char*)midt + (size_t)(colr * 2 + half) * 64;
#pragma unroll 1
    for (int l = 0; l < 29; ++l) {
        const short8 A0h = ld8(ap), A1h = ld8(ap + 16);
        const short8 A0l = ld8(ap + 32), A1l = ld8(ap + 48);
        ap += 4096;

        unsigned plo0 = packhi2(Hv[0], Hv[1]), plo1 = packhi2(Hv[2], Hv[3]);
        unsigned phi0 = packhi2(Hv[4], Hv[5]), phi1 = packhi2(Hv[6], Hv[7]);
        plswap(plo0, phi0); plswap(plo1, phi1);
        const short8 B0h = mk8(plo0, plo1, phi0, phi1);

        unsigned qlo0 = packhi2(lopart(Hv[0]), lopart(Hv[1]));
        unsigned qlo1 = packhi2(lopart(Hv[2]), lopart(Hv[3]));
        unsigned qhi0 = packhi2(lopart(Hv[4]), lopart(Hv[5]));
        unsigned qhi1 = packhi2(lopart(Hv[6]), lopart(Hv[7]));
        plswap(qlo0, qhi0); plswap(qlo1, qhi1);
        const short8 B0l = mk8(qlo0, qlo1, qhi0, qhi1);

        // k16..19 real (half0) + constant-1.0 slots at k20 (B1h) / k21 (B1l) for bias
        const short8 B1h = mk8(half ? 0u : packhi2(Hv[8], Hv[9]),
                               half ? 0u : packhi2(Hv[10], Hv[11]),
                               half ? 0u : 0x00003F80u, 0u);
        const short8 B1l = mk8(half ? 0u : packhi2(lopart(Hv[8]), lopart(Hv[9])),
                               half ? 0u : packhi2(lopart(Hv[10]), lopart(Hv[11])),
                               half ? 0u : 0x3F800000u, 0u);

        f32x16 d;
#pragma unroll
        for (int r = 0; r < 16; ++r) d[r] = 0.f;
        d = MFMA(A0h, B0h, d);
        d = MFMA(A0l, B0h, d);
        d = MFMA(A0h, B0l, d);
        d = MFMA(A1h, B1h, d);
        d = MFMA(A1l, B1h, d);
        d = MFMA(A1h, B1l, d);

        if (l < 28) {
#pragma unroll
            for (int r = 0; r < 16; ++r) Hv[r] = fmaxf(d[r], 0.f);
        } else {
#pragma unroll
            for (int r = 0; r < 16; ++r) {
                const int o = (r & 3) + 8 * (r >> 2) + 4 * half;
                if (o < 10) out[(size_t)row * 10 + o] = d[r];
            }
        }
    }
}

extern "C" void kernel_launch(void* const* d_in, const int* in_sizes, int n_in,
                              void* d_out, int out_size, void* d_ws, size_t ws_size,
                              hipStream_t stream)
{
    const float* x    = (const float*)d_in[0];
    const float* W1   = (const float*)d_in[1];
    const float* b1   = (const float*)d_in[2];
    const float* Wmid = (const float*)d_in[3];
    const float* bmid = (const float*)d_in[4];
    const float* W30  = (const float*)d_in[5];
    const float* b30  = (const float*)d_in[6];
    float* out = (float*)d_out;

    ushort16_t* w1t  = (ushort16_t*)d_ws;                          // 50176 B
    ushort16_t* midt = (ushort16_t*)((char*)d_ws + 50176);         // 118784 B

    const int nrows = in_sizes[0] / 784;
    prepack<<<32, 256, 0, stream>>>(W1, Wmid, bmid, W30, b30, w1t, midt);
    const int tiles = (nrows + 31) / 32;       // 2048
    const int grid  = (tiles + 1) / 2;         // 1024 blocks x (2 tiles * 2 k-waves)
    mlp_main<<<grid, 256, 0, stream>>>(x, b1, w1t, midt, out, nrows);
}